// Round 9
// baseline (292.642 us; speedup 1.0000x reference)
//
#include <hip/hip_runtime.h>

#define NL 64
#define SQ 512
#define BATCH 1024

typedef _Float16 h8    __attribute__((ext_vector_type(8)));
typedef float    f32x4 __attribute__((ext_vector_type(4)));
typedef int      i32x4 __attribute__((ext_vector_type(4)));

#define EXP2F(x)  __builtin_amdgcn_exp2f(x)   // 2^x (v_exp_f32)
#define LOG2F(x)  __builtin_amdgcn_logf(x)    // log2 (v_log_f32)
#define MFMA16(a,b,c) __builtin_amdgcn_mfma_f32_16x16x32_f16((a),(b),(c),0,0,0)

static __device__ __forceinline__ int pkf16(float a, float b) {
    return __builtin_bit_cast(int, __builtin_amdgcn_cvt_pkrtz(a, b));
}

// ---------------------------------------------------------------------------
// Round-15 = round-14 resubmitted verbatim (round-8 bench was an
// infrastructure failure: "MI355X container failed twice" — no compile or
// run happened, so the design is still unmeasured).
//
// Design under test: remove ALL staging intermediaries.
//  - emissions: per-lane DIRECT gather of this lane's own D-fragment,
//    4 x global_load_dwordx4 per step into a statically-indexed q[4][4]
//    FIFO in a FLAT 4-unrolled loop (round-1's proven prefetch shape).
//    Load->use distance = 4 steps (~1000 cyc), 16 loads in flight,
//    compiler-counted vmcnt.
//  - masks: direct int4 gathers, one iteration ahead (no LDS). fwd t=0
//    no-op via (it==0) predicate.
//  - lane(l&15)->all broadcast via ds_bpermute (gfx9-lineage crossbar;
//    permlanex16 is gfx10-only and does not compile on gfx950).
//  - step math (Afr layout, exponent-bit renorm, f16 packs, 2xMFMA)
//    byte-identical to the round-5/6 verified kernel. Zero LDS arrays.
// ---------------------------------------------------------------------------
__global__ __launch_bounds__(64, 1) void crf_scan_mfma(
    const float* __restrict__ emissions,   // [B, S, L]
    const int*   __restrict__ mask,        // [B, S]
    const float* __restrict__ trans,       // [L, L]
    const float* __restrict__ start_t,     // [L]
    const float* __restrict__ end_t,       // [L]
    float* __restrict__ ws_p,              // [2B][64]
    float* __restrict__ ws_c)              // [2B]
{
    const int  blk   = blockIdx.x;         // 0..127
    const bool fwd   = blk < 64;
    const int  grp   = fwd ? blk : blk - 64;
    const int  l  = threadIdx.x;
    const int  cl = l & 15;
    const int  g  = l >> 4;
    const int  chain = grp * 16 + cl;
    const float LOG2E = 1.44269504088896340736f;

    const float* emL = emissions + (size_t)chain * SQ * NL + 4 * g; // + t*NL + 16m
    const int*   mkc = mask + (size_t)chain * SQ;
    const int    bpa = cl * 4;             // bpermute byte addr: lane (l&15)

    // ---- resident A fragments (round-5/6 verified) ----
    h8 Afr[4][2];
#pragma unroll
    for (int m = 0; m < 4; ++m) {
#pragma unroll
        for (int ks = 0; ks < 2; ++ks) {
            i32x4 w;
#pragma unroll
            for (int ep = 0; ep < 4; ++ep) {
                const int e0 = 2*ep, e1 = 2*ep + 1;
                const int k0 = 32*ks + 16*(e0>>2) + 4*g + (e0&3);
                const int k1 = 32*ks + 16*(e1>>2) + 4*g + (e1&3);
                float v0, v1;
                if (fwd) { v0 = __expf(trans[k0*NL + (16*m + cl)]);
                           v1 = __expf(trans[k1*NL + (16*m + cl)]); }
                else     { v0 = __expf(trans[(16*m + cl)*NL + k0]);
                           v1 = __expf(trans[(16*m + cl)*NL + k1]); }
                w[ep] = pkf16(v0, v1);
            }
            Afr[m][ks] = __builtin_bit_cast(h8, w);
        }
    }

    // broadcast value from lane (l&15) to all 64 lanes (verified r5/r6 path)
    auto bc16 = [&](float x) -> unsigned {
        return (unsigned)__builtin_amdgcn_ds_bpermute(bpa, __float_as_int(x));
    };

    // ---- state init (round-5/6 verified) ----
    const f32x4 zz = {0.f, 0.f, 0.f, 0.f};
    f32x4 pD[4];
    float basec = 0.f;
    int   esum  = 0;

    if (fwd) {
        f32x4 s0[4];
#pragma unroll
        for (int m = 0; m < 4; ++m) {
            const f32x4 st = *reinterpret_cast<const f32x4*>(start_t + 16*m + 4*g);
            const f32x4 e0 = *reinterpret_cast<const f32x4*>(
                emissions + (size_t)chain*SQ*NL + 16*m + 4*g);
            s0[m] = st + e0;
        }
        const float anc = __uint_as_float(bc16(s0[0][0]));
        basec = anc * LOG2E;
#pragma unroll
        for (int m = 0; m < 4; ++m)
#pragma unroll
            for (int r = 0; r < 4; ++r)
                pD[m][r] = EXP2F((s0[m][r] - anc) * LOG2E);
    } else {
#pragma unroll
        for (int m = 0; m < 4; ++m) {
            const f32x4 ev = *reinterpret_cast<const f32x4*>(end_t + 16*m + 4*g);
#pragma unroll
            for (int r = 0; r < 4; ++r) pD[m][r] = __expf(ev[r]);
        }
        basec = 0.f;
    }

    // ---- step cores (round-5/6 verified math; ex precomputed by caller) ----
    auto stepF = [&](const f32x4 (&ex)[4], int mm) {
        const unsigned u = bc16(pD[0][0]);
        const int eb = (int)((u >> 23) & 0xffu);
        const float sc = __uint_as_float((unsigned)(251 - eb) << 23);  // 2^(124-eb)
        i32x4 w0, w1;
        w0[0] = pkf16(pD[0][0]*sc, pD[0][1]*sc); w0[1] = pkf16(pD[0][2]*sc, pD[0][3]*sc);
        w0[2] = pkf16(pD[1][0]*sc, pD[1][1]*sc); w0[3] = pkf16(pD[1][2]*sc, pD[1][3]*sc);
        w1[0] = pkf16(pD[2][0]*sc, pD[2][1]*sc); w1[1] = pkf16(pD[2][2]*sc, pD[2][3]*sc);
        w1[2] = pkf16(pD[3][0]*sc, pD[3][1]*sc); w1[3] = pkf16(pD[3][2]*sc, pD[3][3]*sc);
        const h8 B0 = __builtin_bit_cast(h8, w0);
        const h8 B1 = __builtin_bit_cast(h8, w1);
        f32x4 ac[4];
#pragma unroll
        for (int m = 0; m < 4; ++m) {
            ac[m] = MFMA16(Afr[m][0], B0, zz);
            ac[m] = MFMA16(Afr[m][1], B1, ac[m]);
        }
#pragma unroll
        for (int m = 0; m < 4; ++m)
#pragma unroll
            for (int r = 0; r < 4; ++r)
                pD[m][r] = mm ? (ex[m][r] * ac[m][r]) : pD[m][r];
        esum += mm ? (eb - 124) : 0;
    };

    auto stepB = [&](const f32x4 (&ex)[4], int mm) {
        f32x4 scv[4];
#pragma unroll
        for (int m = 0; m < 4; ++m)
#pragma unroll
            for (int r = 0; r < 4; ++r)
                scv[m][r] = ex[m][r] * pD[m][r];
        const unsigned u = bc16(scv[0][0]);
        const int eb = (int)((u >> 23) & 0xffu);
        const float sc = __uint_as_float((unsigned)(251 - eb) << 23);
        i32x4 w0, w1;
        w0[0] = pkf16(scv[0][0]*sc, scv[0][1]*sc); w0[1] = pkf16(scv[0][2]*sc, scv[0][3]*sc);
        w0[2] = pkf16(scv[1][0]*sc, scv[1][1]*sc); w0[3] = pkf16(scv[1][2]*sc, scv[1][3]*sc);
        w1[0] = pkf16(scv[2][0]*sc, scv[2][1]*sc); w1[1] = pkf16(scv[2][2]*sc, scv[2][3]*sc);
        w1[2] = pkf16(scv[3][0]*sc, scv[3][1]*sc); w1[3] = pkf16(scv[3][2]*sc, scv[3][3]*sc);
        const h8 B0 = __builtin_bit_cast(h8, w0);
        const h8 B1 = __builtin_bit_cast(h8, w1);
        f32x4 ac[4];
#pragma unroll
        for (int m = 0; m < 4; ++m) {
            ac[m] = MFMA16(Afr[m][0], B0, zz);
            ac[m] = MFMA16(Afr[m][1], B1, ac[m]);
        }
#pragma unroll
        for (int m = 0; m < 4; ++m)
#pragma unroll
            for (int r = 0; r < 4; ++r)
                pD[m][r] = mm ? ac[m][r] : pD[m][r];
        esum += mm ? (eb - 124) : 0;
    };

    // ---- main loops: flat, statically indexed q[4][4] register FIFO ----
    if (fwd) {
        f32x4 q[4][4];
#pragma unroll
        for (int uu = 0; uu < 4; ++uu)
#pragma unroll
            for (int m = 0; m < 4; ++m)
                q[uu][m] = *reinterpret_cast<const f32x4*>(emL + uu*NL + 16*m);
        i32x4 Mv = *reinterpret_cast<const i32x4*>(mkc);      // steps 0..3

        for (int it = 0; it < 64; ++it) {
            // mask prefetch for next iteration (it=63: reads [256..259],
            // in-bounds, unused)
            const i32x4 Mn = *reinterpret_cast<const i32x4*>(mkc + 4*it + 4);
            const int tb = 4*it + 4;                          // prefetch base
#pragma unroll
            for (int uu = 0; uu < 4; ++uu) {
                f32x4 ex[4];
#pragma unroll
                for (int m = 0; m < 4; ++m)
#pragma unroll
                    for (int r = 0; r < 4; ++r)
                        ex[m][r] = EXP2F(q[uu][m][r] * LOG2E);
                // overwrite q[uu] with step s+4 (it=63: t up to 259,
                // in-bounds rows of this chain, unused)
#pragma unroll
                for (int m = 0; m < 4; ++m)
                    q[uu][m] = *reinterpret_cast<const f32x4*>(
                        emL + (size_t)(tb + uu)*NL + 16*m);
                const int mm = (uu == 0) ? ((it == 0) ? 0 : Mv[0]) : Mv[uu];
                stepF(ex, mm);
            }
            Mv = Mn;
        }
    } else {
        f32x4 q[4][4];
#pragma unroll
        for (int uu = 0; uu < 4; ++uu)
#pragma unroll
            for (int m = 0; m < 4; ++m)
                q[uu][m] = *reinterpret_cast<const f32x4*>(emL + (511-uu)*NL + 16*m);
        i32x4 Mv = *reinterpret_cast<const i32x4*>(mkc + 508); // t 508..511

        for (int it = 0; it < 64; ++it) {
            // it=63: reads [252..255], in-bounds, unused
            const i32x4 Mn = *reinterpret_cast<const i32x4*>(mkc + 504 - 4*it);
            const int tb = 511 - (4*it + 4);                   // prefetch base
#pragma unroll
            for (int uu = 0; uu < 4; ++uu) {
                f32x4 ex[4];
#pragma unroll
                for (int m = 0; m < 4; ++m)
#pragma unroll
                    for (int r = 0; r < 4; ++r)
                        ex[m][r] = EXP2F(q[uu][m][r] * LOG2E);
#pragma unroll
                for (int m = 0; m < 4; ++m)
                    q[uu][m] = *reinterpret_cast<const f32x4*>(
                        emL + (size_t)(tb - uu)*NL + 16*m);
                const int mm = Mv[3 - uu];                     // t = 511-4it-uu
                stepB(ex, mm);
            }
            Mv = Mn;
        }
    }

    // ---- write out (round-5/6 verified) ----
    const int slot = (fwd ? 0 : BATCH) + chain;
#pragma unroll
    for (int m = 0; m < 4; ++m)
        *reinterpret_cast<f32x4*>(ws_p + (size_t)slot*NL + 16*m + 4*g) = pD[m];
    if (g == 0) ws_c[slot] = basec + (float)esum;
}

// out[b] = ln2 * ( c2f + c2b + log2( sum_j pf[j] * pb[j] ) )
__global__ __launch_bounds__(64) void crf_combine(
    const float* __restrict__ ws_p, const float* __restrict__ ws_c,
    float* __restrict__ out)
{
    const int b = blockIdx.x;
    const int j = threadIdx.x;
    float v = ws_p[(size_t)b * NL + j] * ws_p[(size_t)(b + BATCH) * NL + j];
#pragma unroll
    for (int off = 32; off; off >>= 1) v += __shfl_xor(v, off);
    if (j == 0)
        out[b] = 0.69314718055994530942f *
                 (ws_c[b] + ws_c[b + BATCH] + LOG2F(v));
}

extern "C" void kernel_launch(void* const* d_in, const int* in_sizes, int n_in,
                              void* d_out, int out_size, void* d_ws, size_t ws_size,
                              hipStream_t stream) {
    const float* emissions = (const float*)d_in[0];
    const int*   mask      = (const int*)d_in[1];
    const float* trans     = (const float*)d_in[2];
    const float* start_t   = (const float*)d_in[3];
    const float* end_t     = (const float*)d_in[4];
    float* out = (float*)d_out;

    float* ws_p = (float*)d_ws;                    // 2*1024*64 floats
    float* ws_c = ws_p + 2 * BATCH * NL;           // 2*1024 floats

    crf_scan_mfma<<<128, NL, 0, stream>>>(emissions, mask, trans,
                                          start_t, end_t, ws_p, ws_c);
    crf_combine<<<BATCH, NL, 0, stream>>>(ws_p, ws_c, out);
}

// Round 10
// 233.861 us; speedup vs baseline: 1.2514x; 1.2514x over previous
//
#include <hip/hip_runtime.h>

#define NL 64
#define SQ 512
#define BATCH 1024

typedef _Float16 h8    __attribute__((ext_vector_type(8)));
typedef float    f32x4 __attribute__((ext_vector_type(4)));
typedef int      i32x4 __attribute__((ext_vector_type(4)));

#define EXP2F(x)  __builtin_amdgcn_exp2f(x)   // 2^x (v_exp_f32)
#define LOG2F(x)  __builtin_amdgcn_logf(x)    // log2 (v_log_f32)
#define MFMA16(a,b,c) __builtin_amdgcn_mfma_f32_16x16x32_f16((a),(b),(c),0,0,0)

static __device__ __forceinline__ int pkf16(float a, float b) {
    return __builtin_bit_cast(int, __builtin_amdgcn_cvt_pkrtz(a, b));
}

// pinned-issue load: volatile asm cannot be sunk/rematerialized by the
// compiler; output is an SSA value the allocator must keep live.
#define GL(dst, p, OFF) \
    asm volatile("global_load_dwordx4 %0, %1, off offset:" OFF \
                 : "=&v"(dst) : "v"(p) : "memory")

// rule #18: the sched_barrier after the waitcnt is mandatory — without it
// hipcc hoists register-only consumes above the inline-asm wait.
#define WAIT17 do { asm volatile("s_waitcnt vmcnt(17)" ::: "memory"); \
                    __builtin_amdgcn_sched_barrier(0); } while (0)

#define ISSUE_F(qb, Mb, pA, pM) do { \
    GL(qb[0][0], pA, "0");    GL(qb[0][1], pA, "64");   \
    GL(qb[0][2], pA, "128");  GL(qb[0][3], pA, "192");  \
    GL(qb[1][0], pA, "256");  GL(qb[1][1], pA, "320");  \
    GL(qb[1][2], pA, "384");  GL(qb[1][3], pA, "448");  \
    GL(qb[2][0], pA, "512");  GL(qb[2][1], pA, "576");  \
    GL(qb[2][2], pA, "640");  GL(qb[2][3], pA, "704");  \
    GL(qb[3][0], pA, "768");  GL(qb[3][1], pA, "832");  \
    GL(qb[3][2], pA, "896");  GL(qb[3][3], pA, "960");  \
    GL(Mb, pM, "0"); \
} while (0)

#define ISSUE_B(qb, Mb, pA, pM) do { \
    GL(qb[0][0], pA, "0");     GL(qb[0][1], pA, "64");    \
    GL(qb[0][2], pA, "128");   GL(qb[0][3], pA, "192");   \
    GL(qb[1][0], pA, "-256");  GL(qb[1][1], pA, "-192");  \
    GL(qb[1][2], pA, "-128");  GL(qb[1][3], pA, "-64");   \
    GL(qb[2][0], pA, "-512");  GL(qb[2][1], pA, "-448");  \
    GL(qb[2][2], pA, "-384");  GL(qb[2][3], pA, "-320");  \
    GL(qb[3][0], pA, "-768");  GL(qb[3][1], pA, "-704");  \
    GL(qb[3][2], pA, "-640");  GL(qb[3][3], pA, "-576");  \
    GL(Mb, pM, "0"); \
} while (0)

// ---------------------------------------------------------------------------
// Round-16: round-15 + INLINE-ASM staging. Round-9/15 proved the compiler
// sinks any compiler-visible prefetch FIFO (VGPR 84, loads at point-of-use,
// 1500 cyc/step exposed latency). asm volatile loads pin the issue point and
// force the outputs to stay register-resident. Two banks (A/B) alternate in
// a 2x-unrolled loop (no copies): issue 17 loads into the other bank, wait
// vmcnt(17)+sched_barrier, consume this bank (4 steps). Issue->consume
// distance = 4 steps (~1000 cyc) covers L3-warm latency.
// Step math byte-identical to the verified r5/r6/r15 kernel (Afr layout,
// exponent-bit renorm via ds_bpermute anchor broadcast, f16 packs, 2xMFMA).
// ---------------------------------------------------------------------------
__global__ __launch_bounds__(64, 1) void crf_scan_mfma(
    const float* __restrict__ emissions,   // [B, S, L]
    const int*   __restrict__ mask,        // [B, S]
    const float* __restrict__ trans,       // [L, L]
    const float* __restrict__ start_t,     // [L]
    const float* __restrict__ end_t,       // [L]
    float* __restrict__ ws_p,              // [2B][64]
    float* __restrict__ ws_c)              // [2B]
{
    const int  blk   = blockIdx.x;         // 0..127
    const bool fwd   = blk < 64;
    const int  grp   = fwd ? blk : blk - 64;
    const int  l  = threadIdx.x;
    const int  cl = l & 15;
    const int  g  = l >> 4;
    const int  chain = grp * 16 + cl;
    const float LOG2E = 1.44269504088896340736f;

    const float* emL = emissions + (size_t)chain * SQ * NL + 4 * g; // + t*NL + 16m
    const int*   mkc = mask + (size_t)chain * SQ;
    const int    bpa = cl * 4;             // bpermute byte addr: lane (l&15)

    // ---- resident A fragments (r5/r6 verified) ----
    h8 Afr[4][2];
#pragma unroll
    for (int m = 0; m < 4; ++m) {
#pragma unroll
        for (int ks = 0; ks < 2; ++ks) {
            i32x4 w;
#pragma unroll
            for (int ep = 0; ep < 4; ++ep) {
                const int e0 = 2*ep, e1 = 2*ep + 1;
                const int k0 = 32*ks + 16*(e0>>2) + 4*g + (e0&3);
                const int k1 = 32*ks + 16*(e1>>2) + 4*g + (e1&3);
                float v0, v1;
                if (fwd) { v0 = __expf(trans[k0*NL + (16*m + cl)]);
                           v1 = __expf(trans[k1*NL + (16*m + cl)]); }
                else     { v0 = __expf(trans[(16*m + cl)*NL + k0]);
                           v1 = __expf(trans[(16*m + cl)*NL + k1]); }
                w[ep] = pkf16(v0, v1);
            }
            Afr[m][ks] = __builtin_bit_cast(h8, w);
        }
    }

    auto bc16 = [&](float x) -> unsigned {
        return (unsigned)__builtin_amdgcn_ds_bpermute(bpa, __float_as_int(x));
    };

    // ---- state init (r5/r6 verified) ----
    const f32x4 zz = {0.f, 0.f, 0.f, 0.f};
    f32x4 pD[4];
    float basec = 0.f;
    int   esum  = 0;

    if (fwd) {
        f32x4 s0[4];
#pragma unroll
        for (int m = 0; m < 4; ++m) {
            const f32x4 st = *reinterpret_cast<const f32x4*>(start_t + 16*m + 4*g);
            const f32x4 e0 = *reinterpret_cast<const f32x4*>(
                emissions + (size_t)chain*SQ*NL + 16*m + 4*g);
            s0[m] = st + e0;
        }
        const float anc = __uint_as_float(bc16(s0[0][0]));
        basec = anc * LOG2E;
#pragma unroll
        for (int m = 0; m < 4; ++m)
#pragma unroll
            for (int r = 0; r < 4; ++r)
                pD[m][r] = EXP2F((s0[m][r] - anc) * LOG2E);
    } else {
#pragma unroll
        for (int m = 0; m < 4; ++m) {
            const f32x4 ev = *reinterpret_cast<const f32x4*>(end_t + 16*m + 4*g);
#pragma unroll
            for (int r = 0; r < 4; ++r) pD[m][r] = __expf(ev[r]);
        }
        basec = 0.f;
    }

    // ---- step cores (r5/r6 verified math; ex precomputed by caller) ----
    auto stepF = [&](const f32x4 (&ex)[4], int mm) {
        const unsigned u = bc16(pD[0][0]);
        const int eb = (int)((u >> 23) & 0xffu);
        const float sc = __uint_as_float((unsigned)(251 - eb) << 23);  // 2^(124-eb)
        i32x4 w0, w1;
        w0[0] = pkf16(pD[0][0]*sc, pD[0][1]*sc); w0[1] = pkf16(pD[0][2]*sc, pD[0][3]*sc);
        w0[2] = pkf16(pD[1][0]*sc, pD[1][1]*sc); w0[3] = pkf16(pD[1][2]*sc, pD[1][3]*sc);
        w1[0] = pkf16(pD[2][0]*sc, pD[2][1]*sc); w1[1] = pkf16(pD[2][2]*sc, pD[2][3]*sc);
        w1[2] = pkf16(pD[3][0]*sc, pD[3][1]*sc); w1[3] = pkf16(pD[3][2]*sc, pD[3][3]*sc);
        const h8 B0 = __builtin_bit_cast(h8, w0);
        const h8 B1 = __builtin_bit_cast(h8, w1);
        f32x4 ac[4];
#pragma unroll
        for (int m = 0; m < 4; ++m) {
            ac[m] = MFMA16(Afr[m][0], B0, zz);
            ac[m] = MFMA16(Afr[m][1], B1, ac[m]);
        }
#pragma unroll
        for (int m = 0; m < 4; ++m)
#pragma unroll
            for (int r = 0; r < 4; ++r)
                pD[m][r] = mm ? (ex[m][r] * ac[m][r]) : pD[m][r];
        esum += mm ? (eb - 124) : 0;
    };

    auto stepB = [&](const f32x4 (&ex)[4], int mm) {
        f32x4 scv[4];
#pragma unroll
        for (int m = 0; m < 4; ++m)
#pragma unroll
            for (int r = 0; r < 4; ++r)
                scv[m][r] = ex[m][r] * pD[m][r];
        const unsigned u = bc16(scv[0][0]);
        const int eb = (int)((u >> 23) & 0xffu);
        const float sc = __uint_as_float((unsigned)(251 - eb) << 23);
        i32x4 w0, w1;
        w0[0] = pkf16(scv[0][0]*sc, scv[0][1]*sc); w0[1] = pkf16(scv[0][2]*sc, scv[0][3]*sc);
        w0[2] = pkf16(scv[1][0]*sc, scv[1][1]*sc); w0[3] = pkf16(scv[1][2]*sc, scv[1][3]*sc);
        w1[0] = pkf16(scv[2][0]*sc, scv[2][1]*sc); w1[1] = pkf16(scv[2][2]*sc, scv[2][3]*sc);
        w1[2] = pkf16(scv[3][0]*sc, scv[3][1]*sc); w1[3] = pkf16(scv[3][2]*sc, scv[3][3]*sc);
        const h8 B0 = __builtin_bit_cast(h8, w0);
        const h8 B1 = __builtin_bit_cast(h8, w1);
        f32x4 ac[4];
#pragma unroll
        for (int m = 0; m < 4; ++m) {
            ac[m] = MFMA16(Afr[m][0], B0, zz);
            ac[m] = MFMA16(Afr[m][1], B1, ac[m]);
        }
#pragma unroll
        for (int m = 0; m < 4; ++m)
#pragma unroll
            for (int r = 0; r < 4; ++r)
                pD[m][r] = mm ? ac[m][r] : pD[m][r];
        esum += mm ? (eb - 124) : 0;
    };

    auto consumeF = [&](const f32x4 (&qx)[4][4], const i32x4& Mx, bool patch) {
#pragma unroll
        for (int uu = 0; uu < 4; ++uu) {
            f32x4 ex[4];
#pragma unroll
            for (int m = 0; m < 4; ++m)
#pragma unroll
                for (int r = 0; r < 4; ++r)
                    ex[m][r] = EXP2F(qx[uu][m][r] * LOG2E);
            int mm = Mx[uu];
            if (patch && uu == 0) mm = 0;          // t=0 is identity
            stepF(ex, mm);
        }
    };
    auto consumeB = [&](const f32x4 (&qx)[4][4], const i32x4& Mx) {
#pragma unroll
        for (int uu = 0; uu < 4; ++uu) {
            f32x4 ex[4];
#pragma unroll
            for (int m = 0; m < 4; ++m)
#pragma unroll
                for (int r = 0; r < 4; ++r)
                    ex[m][r] = EXP2F(qx[uu][m][r] * LOG2E);
            stepB(ex, Mx[3 - uu]);                 // t = base+3-uu descending
        }
    };

    // drain prologue vmem so the counted discipline starts clean
    asm volatile("s_waitcnt vmcnt(0)" ::: "memory");
    __builtin_amdgcn_sched_barrier(0);

    f32x4 qA[4][4], qB[4][4];
    i32x4 MA, MB;

    if (fwd) {
        const float* pA = emL;                     // row 0
        const int*   pM = mkc;                     // t 0..3
        ISSUE_F(qA, MA, pA, pM); pA += 4 * NL; pM += 4;
        for (int h2 = 0; h2 < 32; ++h2) {
            ISSUE_F(qB, MB, pA, pM); pA += 4 * NL; pM += 4;
            WAIT17;
            consumeF(qA, MA, h2 == 0);             // rows 8h2 .. +3
            ISSUE_F(qA, MA, pA, pM); pA += 4 * NL; pM += 4;
            WAIT17;
            consumeF(qB, MB, false);               // rows 8h2+4 .. +7
        }
    } else {
        const float* pA = emL + (size_t)511 * NL;  // rows 511..508 via -offsets
        const int*   pM = mkc + 508;               // t 508..511
        ISSUE_B(qA, MA, pA, pM); pA -= 4 * NL; pM -= 4;
        for (int h2 = 0; h2 < 32; ++h2) {
            ISSUE_B(qB, MB, pA, pM); pA -= 4 * NL; pM -= 4;
            WAIT17;
            consumeB(qA, MA);                      // t = 511-8h2 .. -3
            ISSUE_B(qA, MA, pA, pM); pA -= 4 * NL; pM -= 4;
            WAIT17;
            consumeB(qB, MB);                      // t = 507-8h2 .. -3
        }
    }

    // ---- write out (r5/r6 verified) ----
    const int slot = (fwd ? 0 : BATCH) + chain;
#pragma unroll
    for (int m = 0; m < 4; ++m)
        *reinterpret_cast<f32x4*>(ws_p + (size_t)slot*NL + 16*m + 4*g) = pD[m];
    if (g == 0) ws_c[slot] = basec + (float)esum;
}

// out[b] = ln2 * ( c2f + c2b + log2( sum_j pf[j] * pb[j] ) )
__global__ __launch_bounds__(64) void crf_combine(
    const float* __restrict__ ws_p, const float* __restrict__ ws_c,
    float* __restrict__ out)
{
    const int b = blockIdx.x;
    const int j = threadIdx.x;
    float v = ws_p[(size_t)b * NL + j] * ws_p[(size_t)(b + BATCH) * NL + j];
#pragma unroll
    for (int off = 32; off; off >>= 1) v += __shfl_xor(v, off);
    if (j == 0)
        out[b] = 0.69314718055994530942f *
                 (ws_c[b] + ws_c[b + BATCH] + LOG2F(v));
}

extern "C" void kernel_launch(void* const* d_in, const int* in_sizes, int n_in,
                              void* d_out, int out_size, void* d_ws, size_t ws_size,
                              hipStream_t stream) {
    const float* emissions = (const float*)d_in[0];
    const int*   mask      = (const int*)d_in[1];
    const float* trans     = (const float*)d_in[2];
    const float* start_t   = (const float*)d_in[3];
    const float* end_t     = (const float*)d_in[4];
    float* out = (float*)d_out;

    float* ws_p = (float*)d_ws;                    // 2*1024*64 floats
    float* ws_c = ws_p + 2 * BATCH * NL;           // 2*1024 floats

    crf_scan_mfma<<<128, NL, 0, stream>>>(emissions, mask, trans,
                                          start_t, end_t, ws_p, ws_c);
    crf_combine<<<BATCH, NL, 0, stream>>>(ws_p, ws_c, out);
}

// Round 12
// 228.105 us; speedup vs baseline: 1.2829x; 1.0252x over previous
//
#include <hip/hip_runtime.h>

#define NL 64
#define SQ 512
#define BATCH 1024
#define TMID 256   // forward owns t=0..255, backward owns t=511..256

typedef __fp16 hf2 __attribute__((ext_vector_type(2)));
typedef int    i32x4 __attribute__((ext_vector_type(4)));

#define EXP2F(x)  __builtin_amdgcn_exp2f(x)   // 2^x (v_exp_f32)
#define LOG2F(x)  __builtin_amdgcn_logf(x)    // log2 (v_log_f32)

__device__ __forceinline__ float lane0_bcast(float v) {
    return __uint_as_float(__builtin_amdgcn_readfirstlane(__float_as_uint(v)));
}

// ---------------------------------------------------------------------------
// Round-18 = round-17 resubmitted verbatim (round-11 bench was an
// infrastructure failure: "MI355X container failed twice" — nothing ran).
//
// Round-17 design: round-1's VERIFIED 103.7us kernel (8-deep emission
// prefetch, int4 masks, exponent-bit renorm) with ONE change: the matvec
// broadcast moves from the VALU pipe to the LDS pipe.
//   was: 32 v_readlane (64 VALU-cyc + SGPR hazards) feeding 32 v_dot2
//   now: pack state as 32 hf2 (DPP pair-swap + cvt_pkrtz, as before),
//        ds_write_b32 from the 32 even lanes (32 lanes -> 32 banks,
//        conflict-free), then 8 wave-uniform ds_read_b128 — same-address
//        reads are HW broadcast (no bank conflict) — feeding the same
//        32 v_dot2 with 8 rotating accumulators.
// Why: round-1 measured 972 cyc/2-wave slot, 660 busy; readlanes are ~half
// the per-step VALU cost. LDS ops run on a separate pipe and overlap with
// the co-resident wave's VALU work. Block = 1 wave, so the xbuf write->read
// needs no barrier (same-wave DS ordering via compiler lgkmcnt).
// MFMA branch abandoned: 16-chain/wave decomposition caps occupancy at 1.3%
// and every staging scheme measured 90%+ memory-latency stall (rounds 3-10).
// ---------------------------------------------------------------------------
__global__ __launch_bounds__(64, 2) void crf_scan(
    const float* __restrict__ emissions,   // [B, S, L]
    const int*   __restrict__ mask,        // [B, S]
    const float* __restrict__ trans,       // [L, L]
    const float* __restrict__ start_t,     // [L]
    const float* __restrict__ end_t,       // [L]
    float* __restrict__ ws_p,              // [2B][64]
    float* __restrict__ ws_c)              // [2B]  (log2-domain offsets)
{
    const int  blk = blockIdx.x;
    const bool fwd = blk < BATCH;
    const int  b   = fwd ? blk : blk - BATCH;
    const int  j   = threadIdx.x;
    const float LOG2E = 1.44269504088896340736f;

    __shared__ int xbuf[32];               // 128B: state as 32 packed hf2

    const float* em = emissions + (size_t)b * SQ * NL;
    const int*   mk = mask + (size_t)b * SQ;

    // ET as 32 packed f16 pairs: fwd lane j = column ET[:,j]; bwd lane i = row.
    hf2 et2[NL / 2];
#pragma unroll
    for (int k = 0; k < NL / 2; ++k) {
        float e0, e1;
        if (fwd) { e0 = __expf(trans[(2*k + 0) * NL + j]);
                   e1 = __expf(trans[(2*k + 1) * NL + j]); }
        else     { e0 = __expf(trans[j * NL + (2*k + 0)]);
                   e1 = __expf(trans[j * NL + (2*k + 1)]); }
        et2[k] = __builtin_amdgcn_cvt_pkrtz(e0, e1);
    }

    // sum_i x_i * et[i]: pack pairs, broadcast via LDS (uniform-address
    // ds_read_b128 = HW broadcast), dot2 with 8 rotating accumulators.
    auto matvec = [&](float xb) -> float {
        int nb = __builtin_amdgcn_update_dpp(0, __float_as_int(xb),
                                             0xB1, 0xF, 0xF, true); // quad_perm(1,0,3,2)
        hf2 pk = __builtin_amdgcn_cvt_pkrtz(xb, __int_as_float(nb));
        if ((j & 1) == 0) xbuf[j >> 1] = __builtin_bit_cast(int, pk);
        i32x4 wv[8];
#pragma unroll
        for (int k = 0; k < 8; ++k)
            wv[k] = ((const i32x4*)xbuf)[k];   // uniform addr -> broadcast
        float acc[8] = {0.f,0.f,0.f,0.f,0.f,0.f,0.f,0.f};
#pragma unroll
        for (int k = 0; k < 8; ++k) {
#pragma unroll
            for (int e = 0; e < 4; ++e) {
                const int d = 4*k + e;
                acc[d & 7] = __builtin_amdgcn_fdot2(
                    __builtin_bit_cast(hf2, wv[k][e]), et2[d], acc[d & 7], false);
            }
        }
        return ((acc[0]+acc[1]) + (acc[2]+acc[3]))
             + ((acc[4]+acc[5]) + (acc[6]+acc[7]));
    };

    float p, base;       // state (f32, renormed each step) + f32 log2 base
    int   esum = 0;      // integer log2-domain renorm accumulator

    if (fwd) {
        // ---- prefetch: peel t=1..3 + group 0 (regs) with masks ----
        float pe1 = em[1*NL + j], pe2 = em[2*NL + j], pe3 = em[3*NL + j];
        int   pm1 = mk[1], pm2 = mk[2], pm3 = mk[3];
        float r0 = em[ 4*NL + j], r1 = em[ 5*NL + j];
        float r2 = em[ 6*NL + j], r3 = em[ 7*NL + j];
        float r4 = em[ 8*NL + j], r5 = em[ 9*NL + j];
        float r6 = em[10*NL + j], r7 = em[11*NL + j];
        int4 M0 = *reinterpret_cast<const int4*>(mk + 4);   // t=4..7
        int4 M1 = *reinterpret_cast<const int4*>(mk + 8);   // t=8..11

        const float s0f = start_t[j] + em[j];               // t = 0
        const float C   = lane0_bcast(s0f);
        p = EXP2F((s0f - C) * LOG2E);  base = C * LOG2E;

        auto step = [&](float r, int m) {
            const float ex = EXP2F(r * LOG2E);              // e^emit
            const unsigned u = __builtin_amdgcn_readfirstlane(__float_as_uint(p));
            const int eb = (int)((u >> 23) & 0xffu);
            const float scale = __uint_as_float((unsigned)(251 - eb) << 23); // 2^(124-eb)
            const float mv = matvec(p * scale);
            if (m) { p = ex * mv; esum += eb - 124; }
        };

        step(pe1, pm1); step(pe2, pm2); step(pe3, pm3);     // t = 1..3

        for (int G = 0; G < 31; ++G) {                      // t = 4+8G .. 11+8G
            const int t0 = 4 + 8 * G;
            const int t8 = t0 + 8;
            const int tA = (t0+12 > 255) ? 255 : t0+12;
            const int tB = (t0+13 > 255) ? 255 : t0+13;
            const int tC = (t0+14 > 255) ? 255 : t0+14;
            const int tD = (t0+15 > 255) ? 255 : t0+15;
            float n0 = em[(t8+0)*NL + j], n1 = em[(t8+1)*NL + j];
            float n2 = em[(t8+2)*NL + j], n3 = em[(t8+3)*NL + j];
            float n4 = em[tA*NL + j],     n5 = em[tB*NL + j];
            float n6 = em[tC*NL + j],     n7 = em[tD*NL + j];
            int4 nM0 = *reinterpret_cast<const int4*>(mk + t8);
            const int tm1 = (t0+12 > 252) ? 252 : t0+12;    // 16B-aligned, in-bounds
            int4 nM1 = *reinterpret_cast<const int4*>(mk + tm1);

            step(r0, M0.x); step(r1, M0.y); step(r2, M0.z); step(r3, M0.w);
            step(r4, M1.x); step(r5, M1.y); step(r6, M1.z); step(r7, M1.w);

            r0=n0; r1=n1; r2=n2; r3=n3; r4=n4; r5=n5; r6=n6; r7=n7;
            M0=nM0; M1=nM1;
        }
        // tail t=252..255
        step(r0, M0.x); step(r1, M0.y); step(r2, M0.z); step(r3, M0.w);
    } else {
        float r0 = em[511*NL + j], r1 = em[510*NL + j];
        float r2 = em[509*NL + j], r3 = em[508*NL + j];
        float r4 = em[507*NL + j], r5 = em[506*NL + j];
        float r6 = em[505*NL + j], r7 = em[504*NL + j];
        int4 Ma = *reinterpret_cast<const int4*>(mk + 508); // {508..511}
        int4 Mb = *reinterpret_cast<const int4*>(mk + 504); // {504..507}

        p = __expf(end_t[j]);  base = 0.f;                  // q_511

        auto step = [&](float r, int m) {
            const float ex = EXP2F(r * LOG2E);
            const float sc = ex * p;                        // scale BEFORE matvec
            const unsigned u = __builtin_amdgcn_readfirstlane(__float_as_uint(sc));
            const int eb = (int)((u >> 23) & 0xffu);
            const float scale = __uint_as_float((unsigned)(251 - eb) << 23); // 2^(124-eb)
            const float mv = matvec(sc * scale);
            if (m) { p = mv; esum += eb - 124; }
        };

        for (int G = 0; G < 32; ++G) {                      // t = 511-8G .. 504-8G
            const int t0 = 511 - 8 * G;
            const int tb = t0 - 8;
            const int te0 = (tb-0 < 256) ? 256 : tb-0;
            const int te1 = (tb-1 < 256) ? 256 : tb-1;
            const int te2 = (tb-2 < 256) ? 256 : tb-2;
            const int te3 = (tb-3 < 256) ? 256 : tb-3;
            const int te4 = (tb-4 < 256) ? 256 : tb-4;
            const int te5 = (tb-5 < 256) ? 256 : tb-5;
            const int te6 = (tb-6 < 256) ? 256 : tb-6;
            const int te7 = (tb-7 < 256) ? 256 : tb-7;
            float n0 = em[te0*NL + j], n1 = em[te1*NL + j];
            float n2 = em[te2*NL + j], n3 = em[te3*NL + j];
            float n4 = em[te4*NL + j], n5 = em[te5*NL + j];
            float n6 = em[te6*NL + j], n7 = em[te7*NL + j];
            const int ta  = (tb-3 < 256) ? 256 : tb-3;      // 16B-aligned
            const int tbb = (tb-7 < 256) ? 256 : tb-7;      // 16B-aligned
            int4 nMa = *reinterpret_cast<const int4*>(mk + ta);
            int4 nMb = *reinterpret_cast<const int4*>(mk + tbb);

            step(r0, Ma.w); step(r1, Ma.z); step(r2, Ma.y); step(r3, Ma.x);
            step(r4, Mb.w); step(r5, Mb.z); step(r6, Mb.y); step(r7, Mb.x);

            r0=n0; r1=n1; r2=n2; r3=n3; r4=n4; r5=n5; r6=n6; r7=n7;
            Ma=nMa; Mb=nMb;
        }
    }

    ws_p[(size_t)blk * NL + j] = p;
    if (j == 0) ws_c[blk] = base + (float)esum;
}

// out[b] = ln2 * ( c2f + c2b + log2( sum_j pf[j] * pb[j] ) )
__global__ __launch_bounds__(64) void crf_combine(
    const float* __restrict__ ws_p, const float* __restrict__ ws_c,
    float* __restrict__ out)
{
    const int b = blockIdx.x;
    const int j = threadIdx.x;
    float v = ws_p[(size_t)b * NL + j] * ws_p[(size_t)(b + BATCH) * NL + j];
#pragma unroll
    for (int off = 32; off; off >>= 1) v += __shfl_xor(v, off);
    if (j == 0)
        out[b] = 0.69314718055994530942f *
                 (ws_c[b] + ws_c[b + BATCH] + LOG2F(v));
}

extern "C" void kernel_launch(void* const* d_in, const int* in_sizes, int n_in,
                              void* d_out, int out_size, void* d_ws, size_t ws_size,
                              hipStream_t stream) {
    const float* emissions = (const float*)d_in[0];
    const int*   mask      = (const int*)d_in[1];
    const float* trans     = (const float*)d_in[2];
    const float* start_t   = (const float*)d_in[3];
    const float* end_t     = (const float*)d_in[4];
    float* out = (float*)d_out;

    float* ws_p = (float*)d_ws;                    // 2*1024*64 floats
    float* ws_c = ws_p + 2 * BATCH * NL;           // 2*1024 floats

    crf_scan<<<2 * BATCH, NL, 0, stream>>>(emissions, mask, trans,
                                           start_t, end_t, ws_p, ws_c);
    crf_combine<<<BATCH, NL, 0, stream>>>(ws_p, ws_c, out);
}